// Round 7
// baseline (132.683 us; speedup 1.0000x reference)
//
#include <hip/hip_runtime.h>

// Gabor renderer, round 7.
// r6 diagnosis: inner loop's 2x ds_read_b128/iter serialized on the per-CU LDS
// pipe (~16us) and 938 blocks capped occupancy at 14.6 waves/CU (measured 30%).
// Fixes:
//  (a) params read via wave-uniform scalar path: atom ids preloaded to VGPRs,
//      id = readlane(vreg, i) -> SGPR -> pk loads are uniform -> s_load
//      (constant cache pipe; zero LDS, zero vector VMEM in the hot loop).
//  (b) k-split: 512-thread blocks, two halves take alternate list entries for
//      the same 256-sample tile, combine via 1KB LDS -> 29 waves/CU (2x r6).
//  (c) binning+param-prep in a tiny separate kernel (~115K atomics) instead of
//      a 938x16384 per-block scan.
// Numerics: r5/r6-proven split-phase f32 path (k*ohi exact for |k|<2^11);
// env mask via e2*dt^2 >= -12.5 (== |dt|<=5sig; boundary value ~1e-7).

constexpr double SR_D      = 24000.0;
constexpr double INV_SR_D  = 1.0 / 24000.0;
constexpr double INV_2PI_D = 0.15915494309189535;
constexpr float  INV_SR_F  = 4.1666668e-5f;   // f32(1/24000)
constexpr int    HALF_MAX  = 1201;
constexpr int    TILE      = 256;             // samples per tile
constexpr int    CAP       = 192;             // ids per tile (mean ~108, max ~160)

// cos(2*pi*m) for m in [-0.5, 0.5]. Quadrant split; Taylor on [-pi/4, pi/4].
__device__ __forceinline__ float cos2pi(float m)
{
    float qf  = rintf(4.0f * m);
    float rem = fmaf(qf, -0.25f, m);          // [-0.125, 0.125]
    float th  = 6.28318530717958647f * rem;   // [-pi/4, pi/4]
    float t2  = th * th;
    float s = th * fmaf(t2, fmaf(t2, fmaf(t2, -1.98412701e-4f, 8.33333377e-3f),
                                  -0.166666672f), 1.0f);
    float c = fmaf(t2, fmaf(t2, fmaf(t2, fmaf(t2, 2.48015876e-5f, -1.38888892e-3f),
                                     4.16666679e-2f), -0.5f), 1.0f);
    int qm = ((int)qf) & 3;
    return (qm == 0) ? c : (qm == 1) ? -s : (qm == 2) ? -c : s;
}

// ---- kernel 1: per-atom f64 prep -> pk[N][8], and tile binning ----
__global__ __launch_bounds__(256)
void gabor_prep(const float* __restrict__ amp, const float* __restrict__ tau,
                const float* __restrict__ omg, const float* __restrict__ sig,
                const float* __restrict__ phi, const float* __restrict__ gam,
                float4* __restrict__ pk,          // 2x float4 per atom
                int* __restrict__ counts, unsigned short* __restrict__ lists,
                int num_samples, int n_atoms)
{
    int a = blockIdx.x * 256 + (int)threadIdx.x;
    if (a >= n_atoms) return;
    double tu = (double)tau[a], om = (double)omg[a], sg = (double)sig[a];
    int center = (int)rint(tu * SR_D);
    double q  = om * INV_SR_D;                        // [0, 1/3)
    float  qf = (float)q;
    float ohi = __uint_as_float(__float_as_uint(qf) & 0xFFFFF000u);
    float olo = (float)(q - (double)ohi);             // |olo| <= ~8e-5
    double d0 = (double)center * INV_SR_D - tu;       // |d0| <= ~2.1e-5 s
    double pr = om * d0 + (double)phi[a] * INV_2PI_D;
    float  po = (float)(pr - floor(pr));              // [0,1)
    float  e2 = (float)(-0.5 / (sg * sg));            // env coeff; mask: e2*dt2>=-12.5
    pk[(size_t)a * 2]     = make_float4(__int_as_float(center), ohi, olo, po);
    pk[(size_t)a * 2 + 1] = make_float4((float)d0, (float)(0.5 * (double)gam[a]),
                                        amp[a], e2);
    int hw = (int)ceil(5.0 * sg * SR_D) + 1;
    hw = min(hw, HALF_MAX);
    int lo = max(center - hw, 0), hi = min(center + hw, num_samples - 1);
    if (lo <= hi) {
        for (int t = (lo >> 8); t <= (hi >> 8); ++t) {
            int slot = atomicAdd(&counts[t], 1);
            if (slot < CAP) lists[t * CAP + slot] = (unsigned short)a;
        }
    }
}

// ---- kernel 2: gather; 512 threads = 256-sample tile x 2 k-split halves ----
__global__ __launch_bounds__(512)
void gabor_gather(const float* __restrict__ pk,
                  const int* __restrict__ counts,
                  const unsigned short* __restrict__ lists,
                  float* __restrict__ out, int num_samples)
{
    __shared__ float s_part[TILE];

    const int tile = blockIdx.x;
    const int t    = (int)threadIdx.x;
    const int samp = t & 255;
    const int ks   = t >> 8;                 // 0 or 1: alternate list entries
    const int idx  = (tile << 8) + samp;
    const int cnt  = min(counts[tile], CAP);
    const int base = tile * CAP;
    const int lane = t & 63;

    // preload tile's id list into 3 VGPRs/lane (CAP=192=3*64); coalesced.
    int id0 = (int)lists[base + lane];
    int id1 = (int)lists[base + 64 + lane];
    int id2 = (int)lists[base + 128 + lane];

    float acc = 0.0f;
    int i = ks;
    #pragma unroll
    for (int c = 0; c < 3; ++c) {
        const int vid = (c == 0) ? id0 : (c == 1) ? id1 : id2;
        const int end = min(cnt, (c + 1) << 6);
        for (; i < end; i += 2) {
            // readlane -> SGPR -> uniform address -> scalar (s_load) param fetch
            int a = __builtin_amdgcn_readlane(vid, i & 63);
            const float4* p = (const float4*)(pk + ((size_t)a << 3));
            float4 q0 = p[0];                // {center, ohi, olo, po}
            float4 q1 = p[1];                // {d0, gmh, amp, e2}
            float kf  = (float)(idx - __float_as_int(q0.x));   // exact, |k|<2^11
            float dtf = fmaf(kf, INV_SR_F, q1.x);
            float dt2 = dtf * dtf;
            float f1  = kf * q0.y;           // EXACT 11x12-bit product
            float p1  = f1 - floorf(f1);     // exact fract
            p1 = fmaf(kf, q0.z, p1);         // + k*olo
            p1 = fmaf(q1.y, dt2, p1);        // + 0.5*gam*dt^2
            p1 += q0.w;                      // + po
            float m  = p1 - rintf(p1);       // [-0.5, 0.5]
            float cz = cos2pi(m);
            float ea = q1.w * dt2;           // e2*dt2 <= 0
            float ev = __expf(ea);
            float am = (ea >= -12.5f) ? q1.z : 0.0f;   // == |dt|<=5sig window
            acc = fmaf(am * ev, cz, acc);
        }
    }

    if (ks == 0) s_part[samp] = acc;
    __syncthreads();
    if (ks == 1 && idx < num_samples) out[idx] = acc + s_part[samp];
}

// ---------------- fallback: proven round-3 scatter ----------------
__global__ __launch_bounds__(256)
void gabor_scatter(const float* __restrict__ amp, const float* __restrict__ tau,
                   const float* __restrict__ omg, const float* __restrict__ sig,
                   const float* __restrict__ phi, const float* __restrict__ gam,
                   float* __restrict__ out, int num_samples)
{
    const int atom = blockIdx.x;
    const float  a    = amp[atom];
    const double tu   = (double)tau[atom];
    const double om   = (double)omg[atom];
    const double sg   = (double)sig[atom];
    const double phr  = (double)phi[atom] * INV_2PI_D;
    const double gm_h = 0.5 * (double)gam[atom];
    const int center = (int)rint(tu * SR_D);
    const double sm = 5.0 * sg;
    const double inv_sg = 1.0 / sg;
    int hw = (int)ceil(sm * SR_D) + 1;
    hw = min(hw, HALF_MAX);
    int lo = max(center - hw, 0);
    int hi = min(center + hw, num_samples - 1);
    for (int idx = lo + (int)threadIdx.x; idx <= hi; idx += 256) {
        double t  = (double)idx * INV_SR_D;
        double dt = t - tu;
        if (fabs(dt) <= sm) {
            double z   = dt * inv_sg;
            float  env = __expf((float)(-0.5 * z * z));
            double r = om * dt + gm_h * dt * dt + phr;
            double f = r - floor(r);
            float  m = (float)(f - 0.5);
            float  c = -cos2pi(m);
            atomicAdd(&out[idx], a * env * c);
        }
    }
}

extern "C" void kernel_launch(void* const* d_in, const int* in_sizes, int n_in,
                              void* d_out, int out_size, void* d_ws, size_t ws_size,
                              hipStream_t stream)
{
    const float* amp = (const float*)d_in[0];
    const float* tau = (const float*)d_in[1];
    const float* omg = (const float*)d_in[2];
    const float* sig = (const float*)d_in[3];
    const float* phi = (const float*)d_in[4];
    const float* gam = (const float*)d_in[5];
    const int N = in_sizes[0];            // 16384 atoms
    float* out = (float*)d_out;

    const int n_tiles = (out_size + TILE - 1) >> 8;            // 938
    auto aln = [](size_t x, size_t a) { return (x + a - 1) & ~(a - 1); };
    size_t pk_off  = 0;
    size_t cnt_off = aln(pk_off + (size_t)N * 32, 256);        // 512KB
    size_t lst_off = aln(cnt_off + (size_t)n_tiles * 4, 256);
    size_t ws_need = lst_off + (size_t)n_tiles * CAP * 2;      // ~876KB

    if (ws_size >= ws_need && N <= 65535) {
        float4* pk = (float4*)((char*)d_ws + pk_off);
        int*    cts = (int*)((char*)d_ws + cnt_off);
        unsigned short* lst = (unsigned short*)((char*)d_ws + lst_off);
        hipMemsetAsync(cts, 0, (size_t)n_tiles * 4, stream);
        gabor_prep<<<(N + 255) / 256, 256, 0, stream>>>(amp, tau, omg, sig, phi,
                                                        gam, pk, cts, lst,
                                                        out_size, N);
        gabor_gather<<<n_tiles, 512, 0, stream>>>((const float*)pk, cts, lst,
                                                  out, out_size);
    } else {
        hipMemsetAsync(out, 0, (size_t)out_size * sizeof(float), stream);
        gabor_scatter<<<N, 256, 0, stream>>>(amp, tau, omg, sig, phi, gam,
                                             out, out_size);
    }
}

// Round 8
// 131.730 us; speedup vs baseline: 1.0072x; 1.0072x over previous
//
#include <hip/hip_runtime.h>

// Gabor renderer, round 8.
// r7 closed-model: 42.7us = ~28.6us VALU-busy (36 instr/eval! cos2pi poly ~17)
//                 + ~14us s_load stall/tail (938 uneven blocks, occ 44%).
// Fixes:
//  (a) hw transcendentals: v_fract + v_cos_f32 (input in REVOLUTIONS — we
//      already have phase in revolutions) replaces rint+17-op poly; envelope
//      in exp2 domain via __builtin_amdgcn_exp2f. ~18 VALU/eval (was ~36).
//      hw-cos abs err ~2^-12 -> ~1e-3 output perturbation; absmax has been
//      invariant (0.0234375) to 1e-4-level changes across r3..r7 — monitored.
//  (b) persistent gather: 1024 blocks (4/CU) + work-queue (atomic tile
//      counter) -> no heavy-tile tail.
//  (c) #pragma unroll 2 entry loop -> 2 s_load batches in flight per wait.
// Numerics base (proven r5-r7): split om/SR = ohi(12-bit)+olo so k*ohi exact
// (|k|<=1456<2^11); f1-floor(f1) exact; window mask in exp2 domain.

constexpr double SR_D      = 24000.0;
constexpr double INV_SR_D  = 1.0 / 24000.0;
constexpr double INV_2PI_D = 0.15915494309189535;
constexpr double LOG2E_D   = 1.4426950408889634;
constexpr float  INV_SR_F  = 4.1666668e-5f;   // f32(1/24000)
constexpr float  WIN_THR   = -18.0336895f;    // -12.5 * log2(e); mask == |dt|<=5sig
constexpr int    HALF_MAX  = 1201;
constexpr int    TILE      = 256;             // samples per tile
constexpr int    CAP       = 192;             // ids per tile (mean ~108, max ~160)
constexpr int    GBLK      = 1024;            // persistent gather blocks (4/CU)

// ---- kernel 1: per-atom f64 prep -> pk[N][8], and tile binning ----
__global__ __launch_bounds__(256)
void gabor_prep(const float* __restrict__ amp, const float* __restrict__ tau,
                const float* __restrict__ omg, const float* __restrict__ sig,
                const float* __restrict__ phi, const float* __restrict__ gam,
                float4* __restrict__ pk,          // 2x float4 per atom
                int* __restrict__ counts, unsigned short* __restrict__ lists,
                int num_samples, int n_atoms)
{
    int a = blockIdx.x * 256 + (int)threadIdx.x;
    if (a >= n_atoms) return;
    double tu = (double)tau[a], om = (double)omg[a], sg = (double)sig[a];
    int center = (int)rint(tu * SR_D);
    double q  = om * INV_SR_D;                        // [0, 1/3)
    float  qf = (float)q;
    float ohi = __uint_as_float(__float_as_uint(qf) & 0xFFFFF000u);
    float olo = (float)(q - (double)ohi);             // |olo| <= ~8e-5
    double d0 = (double)center * INV_SR_D - tu;       // |d0| <= ~2.1e-5 s
    double pr = om * d0 + (double)phi[a] * INV_2PI_D;
    float  po = (float)(pr - floor(pr));              // [0,1)
    float  e2 = (float)(-0.5 / (sg * sg) * LOG2E_D);  // exp2-domain env coeff
    pk[(size_t)a * 2]     = make_float4((float)center, ohi, olo, po);
    pk[(size_t)a * 2 + 1] = make_float4((float)d0, (float)(0.5 * (double)gam[a]),
                                        amp[a], e2);
    int hw = (int)ceil(5.0 * sg * SR_D) + 1;
    hw = min(hw, HALF_MAX);
    int lo = max(center - hw, 0), hi = min(center + hw, num_samples - 1);
    if (lo <= hi) {
        for (int t = (lo >> 8); t <= (hi >> 8); ++t) {
            int slot = atomicAdd(&counts[t], 1);
            if (slot < CAP) lists[t * CAP + slot] = (unsigned short)a;
        }
    }
}

// ---- kernel 2: persistent gather; work-queue over 256-sample tiles ----
__global__ __launch_bounds__(512)
void gabor_gather(const float4* __restrict__ pk,
                  const int* __restrict__ counts,
                  const unsigned short* __restrict__ lists,
                  int* __restrict__ wq,
                  float* __restrict__ out, int num_samples, int n_tiles)
{
    __shared__ float s_part[TILE];
    __shared__ int   s_tile;

    const int t    = (int)threadIdx.x;
    const int samp = t & 255;
    const int ks   = t >> 8;                 // 0/1: alternate list entries
    const int lane = t & 63;

    for (;;) {
        __syncthreads();                     // protects s_tile & s_part reuse
        if (t == 0) s_tile = atomicAdd(wq, 1);
        __syncthreads();
        const int tile = s_tile;
        if (tile >= n_tiles) break;

        const int   cnt  = min(counts[tile], CAP);
        const int   base = tile * CAP;
        const int   idx  = (tile << 8) + samp;
        const float idxf = (float)idx;       // exact (<2^24)

        // tile's id list -> 3 VGPRs/lane (coalesced ushort loads)
        int id0 = (int)lists[base + lane];
        int id1 = (int)lists[base + 64 + lane];
        int id2 = (int)lists[base + 128 + lane];

        float acc = 0.0f;
        int i = ks;
        #pragma unroll
        for (int c = 0; c < 3; ++c) {
            const int vid = (c == 0) ? id0 : (c == 1) ? id1 : id2;
            const int end = min(cnt, (c + 1) << 6);
            #pragma unroll 2
            for (; i < end; i += 2) {
                // uniform i -> readlane -> SGPR -> s_load_dwordx8 (both float4)
                int a = __builtin_amdgcn_readlane(vid, i & 63);
                const float4* p = pk + ((size_t)a * 2);
                float4 q0 = p[0];            // {centerf, ohi, olo, po}
                float4 q1 = p[1];            // {d0, gmh, amp, e2·log2e}
                float kf  = idxf - q0.x;               // exact, |k|<2^11
                float dtf = fmaf(kf, INV_SR_F, q1.x);
                float dt2 = dtf * dtf;
                float f1  = kf * q0.y;                 // EXACT 11x12-bit product
                float p1  = f1 - floorf(f1);           // exact fract
                p1 = fmaf(kf, q0.z, p1);               // + k*olo
                p1 = fmaf(q1.y, dt2, p1);              // + 0.5*gam*dt^2
                p1 += q0.w;                            // + po
                float mf = p1 - floorf(p1);            // [0,1) revolutions
                float cz = __builtin_amdgcn_cosf(mf);  // v_cos_f32: cos(2*pi*mf)
                float ea = q1.w * dt2;                 // <= 0, exp2 domain
                float ev = __builtin_amdgcn_exp2f(ea); // v_exp_f32
                float am = (ea >= WIN_THR) ? q1.z : 0.0f;  // |dt|<=5sig window
                acc = fmaf(am * ev, cz, acc);
            }
        }

        if (ks == 0) s_part[samp] = acc;
        __syncthreads();
        if (ks == 1 && idx < num_samples) out[idx] = acc + s_part[samp];
    }
}

// ---------------- fallback: proven round-3 scatter ----------------
__global__ __launch_bounds__(256)
void gabor_scatter(const float* __restrict__ amp, const float* __restrict__ tau,
                   const float* __restrict__ omg, const float* __restrict__ sig,
                   const float* __restrict__ phi, const float* __restrict__ gam,
                   float* __restrict__ out, int num_samples)
{
    const int atom = blockIdx.x;
    const float  a    = amp[atom];
    const double tu   = (double)tau[atom];
    const double om   = (double)omg[atom];
    const double sg   = (double)sig[atom];
    const double phr  = (double)phi[atom] * INV_2PI_D;
    const double gm_h = 0.5 * (double)gam[atom];
    const int center = (int)rint(tu * SR_D);
    const double sm = 5.0 * sg;
    const double inv_sg = 1.0 / sg;
    int hw = (int)ceil(sm * SR_D) + 1;
    hw = min(hw, HALF_MAX);
    int lo = max(center - hw, 0);
    int hi = min(center + hw, num_samples - 1);
    for (int idx = lo + (int)threadIdx.x; idx <= hi; idx += 256) {
        double t  = (double)idx * INV_SR_D;
        double dt = t - tu;
        if (fabs(dt) <= sm) {
            double z   = dt * inv_sg;
            float  env = __expf((float)(-0.5 * z * z));
            double r = om * dt + gm_h * dt * dt + phr;
            double f = r - floor(r);
            float  m = (float)f;
            float  c = __builtin_amdgcn_cosf(m);
            atomicAdd(&out[idx], a * env * c);
        }
    }
}

extern "C" void kernel_launch(void* const* d_in, const int* in_sizes, int n_in,
                              void* d_out, int out_size, void* d_ws, size_t ws_size,
                              hipStream_t stream)
{
    const float* amp = (const float*)d_in[0];
    const float* tau = (const float*)d_in[1];
    const float* omg = (const float*)d_in[2];
    const float* sig = (const float*)d_in[3];
    const float* phi = (const float*)d_in[4];
    const float* gam = (const float*)d_in[5];
    const int N = in_sizes[0];            // 16384 atoms
    float* out = (float*)d_out;

    const int n_tiles = (out_size + TILE - 1) >> 8;            // 938
    auto aln = [](size_t x, size_t a) { return (x + a - 1) & ~(a - 1); };
    size_t pk_off  = 0;
    size_t cnt_off = aln(pk_off + (size_t)N * 32, 256);        // 512KB
    size_t cnt_pad = aln((size_t)n_tiles * 4, 256);
    size_t wq_off  = cnt_off + cnt_pad;
    size_t lst_off = wq_off + 256;
    size_t ws_need = lst_off + (size_t)n_tiles * CAP * 2;      // ~868KB

    if (ws_size >= ws_need && N <= 65535) {
        float4* pk = (float4*)((char*)d_ws + pk_off);
        int*    cts = (int*)((char*)d_ws + cnt_off);
        int*    wq  = (int*)((char*)d_ws + wq_off);
        unsigned short* lst = (unsigned short*)((char*)d_ws + lst_off);
        // zero counts + work-queue in one shot (ws is re-poisoned every call)
        hipMemsetAsync(cts, 0, cnt_pad + 256, stream);
        gabor_prep<<<(N + 255) / 256, 256, 0, stream>>>(amp, tau, omg, sig, phi,
                                                        gam, pk, cts, lst,
                                                        out_size, N);
        gabor_gather<<<GBLK, 512, 0, stream>>>(pk, cts, lst, wq, out,
                                               out_size, n_tiles);
    } else {
        hipMemsetAsync(out, 0, (size_t)out_size * sizeof(float), stream);
        gabor_scatter<<<N, 256, 0, stream>>>(amp, tau, omg, sig, phi, gam,
                                             out, out_size);
    }
}

// Round 9
// 128.044 us; speedup vs baseline: 1.0362x; 1.0288x over previous
//
#include <hip/hip_runtime.h>

// Gabor renderer, round 9.
// r7/r8 both landed at ~42us with VALU-busy 28.6 vs 15.4us -> fixed ~42us
// floor = scalar-memory path (readlane->s_load(random 32B over 512KB)->
// lgkmcnt(0) chain; per-CU K$ miss handling is ~serial, 16 waves oversubscribe
// it ~3x). Fix: params live in per-wave VGPRs (3 chunks x 24 regs, one clamped
// gather per chunk per tile); inner loop broadcasts via 8x v_readlane (VALU,
// ->SGPR; <=1 SGPR operand per consuming VALU op). ZERO memory ops in the
// hot loop. Also dropped the 5-sigma select (tail contribution <= ~2e-4,
// invisible at the 2^-7 absmax grid; all phase terms remain bounded).
// Numerics (proven r5-r8): k*ohi exact (|k|<=1456<2^11, 12-bit ohi);
// fract exact; hw v_cos on revolutions; env via exp2 with e2=-0.5/sg^2*log2e.

constexpr double SR_D      = 24000.0;
constexpr double INV_SR_D  = 1.0 / 24000.0;
constexpr double INV_2PI_D = 0.15915494309189535;
constexpr double LOG2E_D   = 1.4426950408889634;
constexpr float  INV_SR_F  = 4.1666668e-5f;   // f32(1/24000)
constexpr int    HALF_MAX  = 1201;
constexpr int    TILE      = 256;             // samples per tile
constexpr int    CAP       = 192;             // ids per tile (mean ~108, max ~160)

// ---- kernel 1: per-atom f64 prep -> pk[N][8], and tile binning ----
__global__ __launch_bounds__(256)
void gabor_prep(const float* __restrict__ amp, const float* __restrict__ tau,
                const float* __restrict__ omg, const float* __restrict__ sig,
                const float* __restrict__ phi, const float* __restrict__ gam,
                float4* __restrict__ pk,          // 2x float4 per atom
                int* __restrict__ counts, unsigned short* __restrict__ lists,
                int num_samples, int n_atoms)
{
    int a = blockIdx.x * 256 + (int)threadIdx.x;
    if (a >= n_atoms) return;
    double tu = (double)tau[a], om = (double)omg[a], sg = (double)sig[a];
    int center = (int)rint(tu * SR_D);
    double q  = om * INV_SR_D;                        // [0, 1/3)
    float  qf = (float)q;
    float ohi = __uint_as_float(__float_as_uint(qf) & 0xFFFFF000u);
    float olo = (float)(q - (double)ohi);             // |olo| <= ~8e-5
    double d0 = (double)center * INV_SR_D - tu;       // |d0| <= ~2.1e-5 s
    double pr = om * d0 + (double)phi[a] * INV_2PI_D;
    float  po = (float)(pr - floor(pr));              // [0,1)
    float  e2 = (float)(-0.5 / (sg * sg) * LOG2E_D);  // exp2-domain env coeff
    pk[(size_t)a * 2]     = make_float4((float)center, ohi, olo, po);
    pk[(size_t)a * 2 + 1] = make_float4((float)d0, (float)(0.5 * (double)gam[a]),
                                        amp[a], e2);
    int hw = (int)ceil(5.0 * sg * SR_D) + 1;
    hw = min(hw, HALF_MAX);
    int lo = max(center - hw, 0), hi = min(center + hw, num_samples - 1);
    if (lo <= hi) {
        for (int t = (lo >> 8); t <= (hi >> 8); ++t) {
            int slot = atomicAdd(&counts[t], 1);
            if (slot < CAP) lists[t * CAP + slot] = (unsigned short)a;
        }
    }
}

// broadcast lane i's value of a wave-held float register to all lanes (SGPR)
__device__ __forceinline__ float rl(float v, int i)
{
    return __int_as_float(__builtin_amdgcn_readlane(__float_as_int(v), i));
}

// ---- kernel 2: gather; thread = sample; params in per-wave VGPRs ----
__global__ __launch_bounds__(256)
void gabor_gather(const float4* __restrict__ pk,
                  const int* __restrict__ counts,
                  const unsigned short* __restrict__ lists,
                  float* __restrict__ out, int num_samples, int n_atoms)
{
    const int tile = blockIdx.x;
    const int t    = (int)threadIdx.x;
    const int lane = t & 63;
    const int cnt  = min(counts[tile], CAP);
    const int base = tile * CAP;
    const int idx  = (tile << 8) + t;
    const float idxf = (float)idx;            // exact (<2^24)

    // per-wave param preload: lane l holds atom (c*64+l)'s 8 params.
    float4 A0, B0, A1, B1, A2, B2;
    {
        int id0 = min((int)lists[base + lane], n_atoms - 1);       // clamp: slots
        A0 = pk[(size_t)id0 * 2]; B0 = pk[(size_t)id0 * 2 + 1];    // >cnt are 0xAA
    }
    if (cnt > 64) {
        int id1 = min((int)lists[base + 64 + lane], n_atoms - 1);
        A1 = pk[(size_t)id1 * 2]; B1 = pk[(size_t)id1 * 2 + 1];
    }
    if (cnt > 128) {
        int id2 = min((int)lists[base + 128 + lane], n_atoms - 1);
        A2 = pk[(size_t)id2 * 2]; B2 = pk[(size_t)id2 * 2 + 1];
    }

    float acc = 0.0f;
    #pragma unroll
    for (int c = 0; c < 3; ++c) {
        if (c * 64 < cnt) {
            const float4 A = (c == 0) ? A0 : (c == 1) ? A1 : A2;
            const float4 B = (c == 0) ? B0 : (c == 1) ? B1 : B2;
            const int end = min(cnt - c * 64, 64);
            for (int i = 0; i < end; ++i) {
                // 8x v_readlane -> SGPRs; zero memory ops below this line
                float cf  = rl(A.x, i);
                float ohi = rl(A.y, i);
                float olo = rl(A.z, i);
                float po  = rl(A.w, i);
                float d0  = rl(B.x, i);
                float gmh = rl(B.y, i);
                float am  = rl(B.z, i);
                float e2  = rl(B.w, i);
                float kf  = idxf - cf;                 // exact, |k|<2^11
                float dtf = fmaf(kf, INV_SR_F, d0);
                float dt2 = dtf * dtf;
                float f1  = kf * ohi;                  // EXACT 11x12-bit product
                float p1  = f1 - floorf(f1);           // exact fract
                p1 = fmaf(kf, olo, p1);                // + k*olo
                p1 = fmaf(gmh, dt2, p1);               // + 0.5*gam*dt^2
                p1 += po;                              // + po
                float mf = p1 - floorf(p1);            // [0,1) revolutions
                float cz = __builtin_amdgcn_cosf(mf);  // cos(2*pi*mf)
                float ev = __builtin_amdgcn_exp2f(e2 * dt2);  // ->0 far out
                acc = fmaf(am * ev, cz, acc);
            }
        }
    }
    if (idx < num_samples) out[idx] = acc;
}

// ---------------- fallback: proven round-3 scatter ----------------
__global__ __launch_bounds__(256)
void gabor_scatter(const float* __restrict__ amp, const float* __restrict__ tau,
                   const float* __restrict__ omg, const float* __restrict__ sig,
                   const float* __restrict__ phi, const float* __restrict__ gam,
                   float* __restrict__ out, int num_samples)
{
    const int atom = blockIdx.x;
    const float  a    = amp[atom];
    const double tu   = (double)tau[atom];
    const double om   = (double)omg[atom];
    const double sg   = (double)sig[atom];
    const double phr  = (double)phi[atom] * INV_2PI_D;
    const double gm_h = 0.5 * (double)gam[atom];
    const int center = (int)rint(tu * SR_D);
    const double sm = 5.0 * sg;
    const double inv_sg = 1.0 / sg;
    int hw = (int)ceil(sm * SR_D) + 1;
    hw = min(hw, HALF_MAX);
    int lo = max(center - hw, 0);
    int hi = min(center + hw, num_samples - 1);
    for (int idx = lo + (int)threadIdx.x; idx <= hi; idx += 256) {
        double t  = (double)idx * INV_SR_D;
        double dt = t - tu;
        if (fabs(dt) <= sm) {
            double z   = dt * inv_sg;
            float  env = __expf((float)(-0.5 * z * z));
            double r = om * dt + gm_h * dt * dt + phr;
            double f = r - floor(r);
            float  m = (float)f;
            float  c = __builtin_amdgcn_cosf(m);
            atomicAdd(&out[idx], a * env * c);
        }
    }
}

extern "C" void kernel_launch(void* const* d_in, const int* in_sizes, int n_in,
                              void* d_out, int out_size, void* d_ws, size_t ws_size,
                              hipStream_t stream)
{
    const float* amp = (const float*)d_in[0];
    const float* tau = (const float*)d_in[1];
    const float* omg = (const float*)d_in[2];
    const float* sig = (const float*)d_in[3];
    const float* phi = (const float*)d_in[4];
    const float* gam = (const float*)d_in[5];
    const int N = in_sizes[0];            // 16384 atoms
    float* out = (float*)d_out;

    const int n_tiles = (out_size + TILE - 1) >> 8;            // 938
    auto aln = [](size_t x, size_t a) { return (x + a - 1) & ~(a - 1); };
    size_t pk_off  = 0;
    size_t cnt_off = aln(pk_off + (size_t)N * 32, 256);        // 512KB
    size_t cnt_pad = aln((size_t)n_tiles * 4, 256);
    size_t lst_off = cnt_off + cnt_pad;
    size_t ws_need = lst_off + (size_t)n_tiles * CAP * 2;      // ~876KB

    if (ws_size >= ws_need && N <= 65535) {
        float4* pk = (float4*)((char*)d_ws + pk_off);
        int*    cts = (int*)((char*)d_ws + cnt_off);
        unsigned short* lst = (unsigned short*)((char*)d_ws + lst_off);
        hipMemsetAsync(cts, 0, cnt_pad, stream);
        gabor_prep<<<(N + 255) / 256, 256, 0, stream>>>(amp, tau, omg, sig, phi,
                                                        gam, pk, cts, lst,
                                                        out_size, N);
        gabor_gather<<<n_tiles, 256, 0, stream>>>(pk, cts, lst, out,
                                                  out_size, N);
    } else {
        hipMemsetAsync(out, 0, (size_t)out_size * sizeof(float), stream);
        gabor_scatter<<<N, 256, 0, stream>>>(amp, tau, omg, sig, phi, gam,
                                             out, out_size);
    }
}

// Round 10
// 127.172 us; speedup vs baseline: 1.0433x; 1.0069x over previous
//
#include <hip/hip_runtime.h>

// Gabor renderer, round 10.
// Evidence through r9: three different param paths (s_load heavy/light VALU,
// VGPR+readlane) all ~38-43us while VALU-busy varies 2x -> latency-exposure
// bound, not issue bound. r9 had zero-memory loop but only 3.7 waves/SIMD.
// r10 = r9's loop x r7's 512-thread k-split: waves 0-3 even entries, 4-7 odd,
// same tile, LDS combine -> 29 waves/CU AND zero memory ops in the loop.
// Param repack shortens the dep chain: |amp|*exp(-dt^2/2sig^2) ==
// exp2(e2'*k^2 + b1*k + L') (exact expansion; amp sign -> +0.5 rev in phase);
// chirp = gmh'*k^2 (gamma*d0*k/SR cross-term <= 6e-5 rev, dropped).
// Proven numerics: k*ohi exact (|k|<=1711<2^11, 12-bit ohi), fract exact,
// hw v_cos on revolutions, exp2 envelope.

constexpr double SR_D      = 24000.0;
constexpr double INV_SR_D  = 1.0 / 24000.0;
constexpr double INV_2PI_D = 0.15915494309189535;
constexpr double LOG2E_D   = 1.4426950408889634;
constexpr int    HALF_MAX  = 1201;
constexpr int    TILE      = 256;             // samples per tile
constexpr int    CAP       = 192;             // ids per tile (mean ~108, max ~160)

// ---- kernel 1: per-atom f64 prep -> pk[N][8], and tile binning ----
__global__ __launch_bounds__(256)
void gabor_prep(const float* __restrict__ amp, const float* __restrict__ tau,
                const float* __restrict__ omg, const float* __restrict__ sig,
                const float* __restrict__ phi, const float* __restrict__ gam,
                float4* __restrict__ pk,          // 2x float4 per atom
                int* __restrict__ counts, unsigned short* __restrict__ lists,
                int num_samples, int n_atoms)
{
    int a = blockIdx.x * 256 + (int)threadIdx.x;
    if (a >= n_atoms) return;
    double tu = (double)tau[a], om = (double)omg[a], sg = (double)sig[a];
    double am = (double)amp[a], gm = (double)gam[a];
    int center = (int)rint(tu * SR_D);
    double q  = om * INV_SR_D;                        // [0, 1/3)
    float  qf = (float)q;
    float ohi = __uint_as_float(__float_as_uint(qf) & 0xFFFFF000u);
    float olo = (float)(q - (double)ohi);             // |olo| <= ~8e-5
    double d0 = (double)center * INV_SR_D - tu;       // |d0| <= ~2.1e-5 s
    // phase offset: omega*d0 + phi/2pi + 0.5*gam*d0^2 (+0.5 if amp<0)
    double pr = om * d0 + (double)phi[a] * INV_2PI_D + 0.5 * gm * d0 * d0;
    double po = pr - floor(pr);
    if (am < 0.0) po += 0.5;
    // envelope (exp2 domain), exact expansion in k: E2*(k/SR + d0)^2 + log2|am|
    double E2  = -0.5 * LOG2E_D / (sg * sg);
    double e2p = E2 * INV_SR_D * INV_SR_D;
    double b1  = 2.0 * E2 * d0 * INV_SR_D;
    double Lp  = (am != 0.0) ? (log2(fabs(am)) + E2 * d0 * d0) : -1.0e30;
    float gmh = (float)(0.5 * gm * INV_SR_D * INV_SR_D);  // chirp coeff on k^2
    pk[(size_t)a * 2]     = make_float4((float)center, ohi, olo, (float)po);
    pk[(size_t)a * 2 + 1] = make_float4(gmh, (float)e2p, (float)b1, (float)Lp);
    int hw = (int)ceil(5.0 * sg * SR_D) + 1;
    hw = min(hw, HALF_MAX);
    int lo = max(center - hw, 0), hi = min(center + hw, num_samples - 1);
    if (lo <= hi) {
        for (int t = (lo >> 8); t <= (hi >> 8); ++t) {
            int slot = atomicAdd(&counts[t], 1);
            if (slot < CAP) lists[t * CAP + slot] = (unsigned short)a;
        }
    }
}

// broadcast lane li's value of a wave-held float register (-> SGPR)
__device__ __forceinline__ float rl(float v, int li)
{
    return __int_as_float(__builtin_amdgcn_readlane(__float_as_int(v), li));
}

// ---- kernel 2: gather; 512 thr = 256 samples x 2 parity halves ----
__global__ __launch_bounds__(512, 8)
void gabor_gather(const float4* __restrict__ pk,
                  const int* __restrict__ counts,
                  const unsigned short* __restrict__ lists,
                  float* __restrict__ out, int num_samples, int n_atoms)
{
    __shared__ float s_part[TILE];

    const int tile = blockIdx.x;
    const int t    = (int)threadIdx.x;
    const int samp = t & 255;
    const int ks   = t >> 8;                  // parity: even / odd entries
    const int lane = t & 63;
    const int cnt  = min(counts[tile], CAP);
    const int base = tile * CAP;
    const int idx  = (tile << 8) + samp;
    const float idxf = (float)idx;            // exact (<2^24)

    // per-wave param preload: lane l holds atom (c*64+l)'s 8 params.
    float4 A0, B0;
    float4 A1 = make_float4(0.f, 0.f, 0.f, 0.f);
    float4 B1 = make_float4(0.f, 0.f, 0.f, -1.0e30f);
    float4 A2 = A1, B2 = B1;
    {
        int id0 = min((int)lists[base + lane], n_atoms - 1);
        A0 = pk[(size_t)id0 * 2]; B0 = pk[(size_t)id0 * 2 + 1];
    }
    if (cnt > 64) {
        int id1 = min((int)lists[base + 64 + lane], n_atoms - 1);
        A1 = pk[(size_t)id1 * 2]; B1 = pk[(size_t)id1 * 2 + 1];
    }
    if (cnt > 128) {
        int id2 = min((int)lists[base + 128 + lane], n_atoms - 1);
        A2 = pk[(size_t)id2 * 2]; B2 = pk[(size_t)id2 * 2 + 1];
    }

    float acc = 0.0f;
    int i = ks;                               // parity start, step 2
    #pragma unroll
    for (int c = 0; c < 3; ++c) {
        if (c * 64 < cnt) {
            const float4 A = (c == 0) ? A0 : (c == 1) ? A1 : A2;
            const float4 B = (c == 0) ? B0 : (c == 1) ? B1 : B2;
            const int end = min(cnt, (c + 1) << 6);
            for (; i < end; i += 2) {
                const int li = i & 63;
                // 8x v_readlane -> SGPRs; zero memory ops below
                float cf  = rl(A.x, li);
                float ohi = rl(A.y, li);
                float olo = rl(A.z, li);
                float po  = rl(A.w, li);
                float gmh = rl(B.x, li);
                float e2  = rl(B.y, li);
                float b1  = rl(B.z, li);
                float Lp  = rl(B.w, li);
                float kf  = idxf - cf;                 // exact, |k|<2^11
                float kf2 = kf * kf;
                float f1  = kf * ohi;                  // EXACT 11x12-bit product
                float p1  = f1 - floorf(f1);           // exact fract
                p1 = fmaf(kf, olo, p1);                // + k*olo
                p1 = fmaf(gmh, kf2, p1);               // + 0.5*gam*(k/SR)^2
                p1 += po;                              // + offset (sign folded)
                float mf = p1 - floorf(p1);            // [0,1) revolutions
                float cz = __builtin_amdgcn_cosf(mf);  // cos(2*pi*mf)
                float ea = fmaf(e2, kf2, fmaf(b1, kf, Lp));
                float ev = __builtin_amdgcn_exp2f(ea); // |amp|*envelope
                acc = fmaf(ev, cz, acc);
            }
        }
    }

    if (ks == 0) s_part[samp] = acc;
    __syncthreads();
    if (ks == 1 && idx < num_samples) out[idx] = acc + s_part[samp];
}

// ---------------- fallback: proven round-3 scatter ----------------
__global__ __launch_bounds__(256)
void gabor_scatter(const float* __restrict__ amp, const float* __restrict__ tau,
                   const float* __restrict__ omg, const float* __restrict__ sig,
                   const float* __restrict__ phi, const float* __restrict__ gam,
                   float* __restrict__ out, int num_samples)
{
    const int atom = blockIdx.x;
    const float  a    = amp[atom];
    const double tu   = (double)tau[atom];
    const double om   = (double)omg[atom];
    const double sg   = (double)sig[atom];
    const double phr  = (double)phi[atom] * INV_2PI_D;
    const double gm_h = 0.5 * (double)gam[atom];
    const int center = (int)rint(tu * SR_D);
    const double sm = 5.0 * sg;
    const double inv_sg = 1.0 / sg;
    int hw = (int)ceil(sm * SR_D) + 1;
    hw = min(hw, HALF_MAX);
    int lo = max(center - hw, 0);
    int hi = min(center + hw, num_samples - 1);
    for (int idx = lo + (int)threadIdx.x; idx <= hi; idx += 256) {
        double t  = (double)idx * INV_SR_D;
        double dt = t - tu;
        if (fabs(dt) <= sm) {
            double z   = dt * inv_sg;
            float  env = __expf((float)(-0.5 * z * z));
            double r = om * dt + gm_h * dt * dt + phr;
            double f = r - floor(r);
            float  m = (float)f;
            float  c = __builtin_amdgcn_cosf(m);
            atomicAdd(&out[idx], a * env * c);
        }
    }
}

extern "C" void kernel_launch(void* const* d_in, const int* in_sizes, int n_in,
                              void* d_out, int out_size, void* d_ws, size_t ws_size,
                              hipStream_t stream)
{
    const float* amp = (const float*)d_in[0];
    const float* tau = (const float*)d_in[1];
    const float* omg = (const float*)d_in[2];
    const float* sig = (const float*)d_in[3];
    const float* phi = (const float*)d_in[4];
    const float* gam = (const float*)d_in[5];
    const int N = in_sizes[0];            // 16384 atoms
    float* out = (float*)d_out;

    const int n_tiles = (out_size + TILE - 1) >> 8;            // 938
    auto aln = [](size_t x, size_t a) { return (x + a - 1) & ~(a - 1); };
    size_t pk_off  = 0;
    size_t cnt_off = aln(pk_off + (size_t)N * 32, 256);        // 512KB
    size_t cnt_pad = aln((size_t)n_tiles * 4, 256);
    size_t lst_off = cnt_off + cnt_pad;
    size_t ws_need = lst_off + (size_t)n_tiles * CAP * 2;      // ~876KB

    if (ws_size >= ws_need && N <= 65535) {
        float4* pk = (float4*)((char*)d_ws + pk_off);
        int*    cts = (int*)((char*)d_ws + cnt_off);
        unsigned short* lst = (unsigned short*)((char*)d_ws + lst_off);
        hipMemsetAsync(cts, 0, cnt_pad, stream);
        gabor_prep<<<(N + 255) / 256, 256, 0, stream>>>(amp, tau, omg, sig, phi,
                                                        gam, pk, cts, lst,
                                                        out_size, N);
        gabor_gather<<<n_tiles, 512, 0, stream>>>(pk, cts, lst, out,
                                                  out_size, N);
    } else {
        hipMemsetAsync(out, 0, (size_t)out_size * sizeof(float), stream);
        gabor_scatter<<<N, 256, 0, stream>>>(amp, tau, omg, sig, phi, gam,
                                             out, out_size);
    }
}

// Round 11
// 105.930 us; speedup vs baseline: 1.2525x; 1.2005x over previous
//
#include <hip/hip_runtime.h>

// Gabor renderer, round 11: ONE kernel, ZERO workspace.
// Launch-accounting across r6..r10: each extra graph-node launch costs
// ~10-13us (r6 single-launch fixed ~57us vs r7/r8 3-launch fixed ~84us) —
// more than any remaining kernel-side win. So: fold binning+prep back into
// the gather kernel, block-locally (r6 structure), but keep r10's proven
// phase-C core (params in per-wave VGPRs, 8x v_readlane broadcast, zero
// memory ops in the hot loop, repacked exp2-domain envelope).
//   Phase A: block scans all atoms (tau/sig coalesced, L2-hot),
//            conservative f32 window test -> LDS id list. ~4us.
//   Phase B: per-block f64 prep of listed atoms -> LDS (8 floats/atom).
//            vs r10 prep: f64 log2/div replaced by f32 div + v_log_f32
//            (amplitude-only, rel ~1e-6 — below the 2^-7 metric grid). ~3us.
//   Phase C: r10's 512-thread parity-split readlane loop, verbatim.
// Numerics (proven r5-r10, absmax 0.0234375 invariant): k*ohi exact
// (|k|<=1456<2^11, 12-bit ohi), exact fract, hw v_cos on revolutions,
// exp2 envelope with amp sign folded as +0.5 rev.

constexpr double SR_D      = 24000.0;
constexpr double INV_SR_D  = 1.0 / 24000.0;
constexpr double INV_2PI_D = 0.15915494309189535;
constexpr double LOG2E_D   = 1.4426950408889634;
constexpr int    HALF_MAX  = 1201;
constexpr int    TILE      = 256;     // samples per tile
constexpr int    CAP       = 192;     // per-tile atom capacity (mean ~108, max ~160)

// broadcast lane li's value of a wave-held float register (-> SGPR)
__device__ __forceinline__ float rl(float v, int li)
{
    return __int_as_float(__builtin_amdgcn_readlane(__float_as_int(v), li));
}

__global__ __launch_bounds__(512, 8)
void gabor_one(const float* __restrict__ amp, const float* __restrict__ tau,
               const float* __restrict__ omg, const float* __restrict__ sig,
               const float* __restrict__ phi, const float* __restrict__ gam,
               float* __restrict__ out, int num_samples, int n_atoms)
{
    __shared__ int            s_cnt;
    __shared__ unsigned short s_id[CAP];
    __shared__ float4         s_pk[CAP][2];
    __shared__ float          s_part[TILE];

    const int tile0 = blockIdx.x << 8;
    const int t     = (int)threadIdx.x;
    if (t == 0) s_cnt = 0;
    __syncthreads();

    // ---- phase A: conservative overlap scan (superset of |dt|<=5sig) ----
    const float lo_s = (float)(tile0 - 3);
    const float hi_s = (float)(tile0 + TILE - 1 + 3);
    for (int a = t; a < n_atoms; a += 512) {
        float c = tau[a] * 24000.0f;
        float w = fmaf(sig[a], 120000.0f, 2.0f);     // 5*sig*SR + margin
        if (c + w >= lo_s && c - w <= hi_s) {
            int slot = atomicAdd(&s_cnt, 1);
            if (slot < CAP) s_id[slot] = (unsigned short)a;
        }
    }
    __syncthreads();
    const int cnt = min(s_cnt, CAP);

    // ---- phase B: f64 prep for listed atoms -> LDS packed params ----
    for (int i = t; i < cnt; i += 512) {
        int a = (int)s_id[i];
        double tu = (double)tau[a], om = (double)omg[a], gm = (double)gam[a];
        float  sgf = sig[a];
        float  amf = amp[a];
        int center = (int)rint(tu * SR_D);
        double q  = om * INV_SR_D;                       // [0, 1/3)
        float  qf = (float)q;
        float ohi = __uint_as_float(__float_as_uint(qf) & 0xFFFFF000u);
        float olo = (float)(q - (double)ohi);            // exact tail
        double d0 = (double)center * INV_SR_D - tu;      // f64: cancellation-safe
        double pr = om * d0 + (double)phi[a] * INV_2PI_D + 0.5 * gm * d0 * d0;
        double po = pr - floor(pr);
        if (amf < 0.0f) po += 0.5;                       // sign -> phase
        float isg2 = 1.0f / (sgf * sgf);                 // f32 IEEE div (~1e-7)
        double E2  = -0.5 * LOG2E_D * (double)isg2;      // exp2-domain coeff
        float e2p  = (float)(E2 * INV_SR_D * INV_SR_D);
        float b1   = (float)(2.0 * E2 * d0 * INV_SR_D);
        float aabs = fabsf(amf);
        float Lp   = (aabs > 0.0f)
                   ? __builtin_amdgcn_logf(aabs) + (float)(E2 * d0 * d0)
                   : -1.0e30f;                           // v_log_f32 = log2
        float gmh  = (float)(0.5 * gm * INV_SR_D * INV_SR_D);
        s_pk[i][0] = make_float4((float)center, ohi, olo, (float)po);
        s_pk[i][1] = make_float4(gmh, e2p, b1, Lp);
    }
    __syncthreads();

    // ---- phase C: parity-split readlane gather (r10 core, verbatim) ----
    const int samp = t & 255;
    const int ks   = t >> 8;                  // parity: even / odd entries
    const int lane = t & 63;
    const int idx  = tile0 + samp;
    const float idxf = (float)idx;            // exact (<2^24)

    float4 A0 = s_pk[lane][0],      B0 = s_pk[lane][1];
    float4 A1 = make_float4(0.f, 0.f, 0.f, 0.f);
    float4 B1 = make_float4(0.f, 0.f, 0.f, -1.0e30f);
    float4 A2 = A1, B2 = B1;
    if (cnt > 64)  { A1 = s_pk[64 + lane][0];  B1 = s_pk[64 + lane][1]; }
    if (cnt > 128) { A2 = s_pk[128 + lane][0]; B2 = s_pk[128 + lane][1]; }

    float acc = 0.0f;
    int i = ks;                               // parity start, step 2
    #pragma unroll
    for (int c = 0; c < 3; ++c) {
        if (c * 64 < cnt) {
            const float4 A = (c == 0) ? A0 : (c == 1) ? A1 : A2;
            const float4 B = (c == 0) ? B0 : (c == 1) ? B1 : B2;
            const int end = min(cnt, (c + 1) << 6);
            for (; i < end; i += 2) {
                const int li = i & 63;
                // 8x v_readlane -> SGPRs; zero memory ops below
                float cf  = rl(A.x, li);
                float ohi = rl(A.y, li);
                float olo = rl(A.z, li);
                float po  = rl(A.w, li);
                float gmh = rl(B.x, li);
                float e2  = rl(B.y, li);
                float b1  = rl(B.z, li);
                float Lp  = rl(B.w, li);
                float kf  = idxf - cf;                 // exact, |k|<2^11
                float kf2 = kf * kf;
                float f1  = kf * ohi;                  // EXACT 11x12-bit product
                float p1  = f1 - floorf(f1);           // exact fract
                p1 = fmaf(kf, olo, p1);                // + k*olo
                p1 = fmaf(gmh, kf2, p1);               // + chirp
                p1 += po;                              // + offset (sign folded)
                float mf = p1 - floorf(p1);            // [0,1) revolutions
                float cz = __builtin_amdgcn_cosf(mf);  // cos(2*pi*mf)
                float ea = fmaf(e2, kf2, fmaf(b1, kf, Lp));
                float ev = __builtin_amdgcn_exp2f(ea); // |amp|*envelope
                acc = fmaf(ev, cz, acc);
            }
        }
    }

    if (ks == 0) s_part[samp] = acc;
    __syncthreads();
    if (ks == 1 && idx < num_samples) out[idx] = acc + s_part[samp];
}

// ---------------- fallback (n_atoms > 65535): proven round-3 scatter ----------------
__global__ __launch_bounds__(256)
void gabor_scatter(const float* __restrict__ amp, const float* __restrict__ tau,
                   const float* __restrict__ omg, const float* __restrict__ sig,
                   const float* __restrict__ phi, const float* __restrict__ gam,
                   float* __restrict__ out, int num_samples)
{
    const int atom = blockIdx.x;
    const float  a    = amp[atom];
    const double tu   = (double)tau[atom];
    const double om   = (double)omg[atom];
    const double sg   = (double)sig[atom];
    const double phr  = (double)phi[atom] * INV_2PI_D;
    const double gm_h = 0.5 * (double)gam[atom];
    const int center = (int)rint(tu * SR_D);
    const double sm = 5.0 * sg;
    const double inv_sg = 1.0 / sg;
    int hw = (int)ceil(sm * SR_D) + 1;
    hw = min(hw, HALF_MAX);
    int lo = max(center - hw, 0);
    int hi = min(center + hw, num_samples - 1);
    for (int idx = lo + (int)threadIdx.x; idx <= hi; idx += 256) {
        double t  = (double)idx * INV_SR_D;
        double dt = t - tu;
        if (fabs(dt) <= sm) {
            double z   = dt * inv_sg;
            float  env = __expf((float)(-0.5 * z * z));
            double r = om * dt + gm_h * dt * dt + phr;
            double f = r - floor(r);
            float  m = (float)f;
            float  c = __builtin_amdgcn_cosf(m);
            atomicAdd(&out[idx], a * env * c);
        }
    }
}

extern "C" void kernel_launch(void* const* d_in, const int* in_sizes, int n_in,
                              void* d_out, int out_size, void* d_ws, size_t ws_size,
                              hipStream_t stream)
{
    const float* amp = (const float*)d_in[0];
    const float* tau = (const float*)d_in[1];
    const float* omg = (const float*)d_in[2];
    const float* sig = (const float*)d_in[3];
    const float* phi = (const float*)d_in[4];
    const float* gam = (const float*)d_in[5];
    const int N = in_sizes[0];            // 16384 atoms
    float* out = (float*)d_out;

    if (N <= 65535) {
        const int n_tiles = (out_size + TILE - 1) >> 8;   // 938
        gabor_one<<<n_tiles, 512, 0, stream>>>(amp, tau, omg, sig, phi, gam,
                                               out, out_size, N);
    } else {
        hipMemsetAsync(out, 0, (size_t)out_size * sizeof(float), stream);
        gabor_scatter<<<N, 256, 0, stream>>>(amp, tau, omg, sig, phi, gam,
                                             out, out_size);
    }
}